// Round 1
// baseline (5133.416 us; speedup 1.0000x reference)
//
#include <hip/hip_runtime.h>

// Edge scatter-add: out[i] += charges[j]*(0.5/d); out[j] += charges[i]*(0.5/d)
// N_CHANNELS = 4 (float4-aligned rows). Output zeroed via hipMemsetAsync
// (harness poisons d_out with 0xAA before every timed launch).

#define NCH 4

__global__ __launch_bounds__(256) void edge_scatter_kernel(
    const float4* __restrict__ charges,   // [N_ATOMS] as float4 rows
    const int2*  __restrict__ nbr,        // [E] (i,j)
    const float* __restrict__ dist,       // [E]
    float* __restrict__ out,              // [N_ATOMS*4]
    int n_edges)
{
    int e = blockIdx.x * blockDim.x + threadIdx.x;
    if (e >= n_edges) return;

    int2  ij = nbr[e];
    float w  = 0.5f / dist[e];

    float4 cj = charges[ij.y];
    float4 ci = charges[ij.x];

    float* oi = out + (size_t)ij.x * NCH;
    float* oj = out + (size_t)ij.y * NCH;

    atomicAdd(oi + 0, cj.x * w);
    atomicAdd(oi + 1, cj.y * w);
    atomicAdd(oi + 2, cj.z * w);
    atomicAdd(oi + 3, cj.w * w);

    atomicAdd(oj + 0, ci.x * w);
    atomicAdd(oj + 1, ci.y * w);
    atomicAdd(oj + 2, ci.z * w);
    atomicAdd(oj + 3, ci.w * w);
}

extern "C" void kernel_launch(void* const* d_in, const int* in_sizes, int n_in,
                              void* d_out, int out_size, void* d_ws, size_t ws_size,
                              hipStream_t stream)
{
    // setup_inputs order: charges, cell, positions, neighbor_indices, neighbor_distances
    const float4* charges = (const float4*)d_in[0];
    const int2*   nbr     = (const int2*)d_in[3];
    const float*  dist    = (const float*)d_in[4];
    float*        out     = (float*)d_out;

    int n_edges = in_sizes[4];          // 12,800,000

    // Zero the accumulator (d_out is poisoned 0xAA before every launch).
    hipMemsetAsync(d_out, 0, (size_t)out_size * sizeof(float), stream);

    int block = 256;
    int grid  = (n_edges + block - 1) / block;
    edge_scatter_kernel<<<grid, block, 0, stream>>>(charges, nbr, dist, out, n_edges);
}

// Round 2
// 5130.735 us; speedup vs baseline: 1.0005x; 1.0005x over previous
//
#include <hip/hip_runtime.h>

// Edge scatter-add: out[i] += charges[j]*(0.5/d); out[j] += charges[i]*(0.5/d)
//
// Round-1 learning: agent-scope atomicAdd write-throughs to memory-side
// (WRITE_SIZE 3.28 GB = 102.4M atomics x 32B, 674 GB/s ceiling -> 5 ms).
// Round-2: per-XCD private replicas in d_ws + WORKGROUP-scope f32 atomics,
// which stay in the local (per-XCD) L2. Replica = 3.2 MB fits the 4 MiB
// per-XCD L2, so atomics run at L2 rate; writeback only on kernel end.
// A second kernel reduces the 8 replicas into d_out.

#define NCH    4
#define NREP   8          // one replica per XCD

__device__ __forceinline__ unsigned xcc_id() {
    unsigned x;
    asm volatile("s_getreg_b32 %0, hwreg(HW_REG_XCC_ID, 0, 4)" : "=s"(x));
    return x & (NREP - 1);
}

__device__ __forceinline__ void at_add_wg(float* p, float v) {
    // Workgroup scope: no cross-XCD coherence required -> compiler may keep
    // the atomic cached in the local TCC (no sc1 write-through).
    __hip_atomic_fetch_add(p, v, __ATOMIC_RELAXED, __HIP_MEMORY_SCOPE_WORKGROUP);
}

__global__ __launch_bounds__(256) void edge_scatter_rep(
    const float4* __restrict__ charges,   // [N_ATOMS]
    const int2*  __restrict__ nbr,        // [E]
    const float* __restrict__ dist,       // [E]
    float* __restrict__ rep,              // [NREP][N_ATOMS*NCH]
    int n_edges, int atoms_nch)
{
    int e = blockIdx.x * blockDim.x + threadIdx.x;
    if (e >= n_edges) return;

    float* r = rep + (size_t)xcc_id() * atoms_nch;

    int2  ij = nbr[e];
    float w  = 0.5f / dist[e];
    float4 cj = charges[ij.y];
    float4 ci = charges[ij.x];

    float* oi = r + (size_t)ij.x * NCH;
    float* oj = r + (size_t)ij.y * NCH;

    at_add_wg(oi + 0, cj.x * w);
    at_add_wg(oi + 1, cj.y * w);
    at_add_wg(oi + 2, cj.z * w);
    at_add_wg(oi + 3, cj.w * w);

    at_add_wg(oj + 0, ci.x * w);
    at_add_wg(oj + 1, ci.y * w);
    at_add_wg(oj + 2, ci.z * w);
    at_add_wg(oj + 3, ci.w * w);
}

// Fallback (ws too small): round-1 agent-scope path, correct but slow.
__global__ __launch_bounds__(256) void edge_scatter_agent(
    const float4* __restrict__ charges,
    const int2*  __restrict__ nbr,
    const float* __restrict__ dist,
    float* __restrict__ out,
    int n_edges)
{
    int e = blockIdx.x * blockDim.x + threadIdx.x;
    if (e >= n_edges) return;
    int2  ij = nbr[e];
    float w  = 0.5f / dist[e];
    float4 cj = charges[ij.y];
    float4 ci = charges[ij.x];
    float* oi = out + (size_t)ij.x * NCH;
    float* oj = out + (size_t)ij.y * NCH;
    atomicAdd(oi + 0, cj.x * w);
    atomicAdd(oi + 1, cj.y * w);
    atomicAdd(oi + 2, cj.z * w);
    atomicAdd(oi + 3, cj.w * w);
    atomicAdd(oj + 0, ci.x * w);
    atomicAdd(oj + 1, ci.y * w);
    atomicAdd(oj + 2, ci.z * w);
    atomicAdd(oj + 3, ci.w * w);
}

// out4[k] = sum over replicas (as float4)
__global__ __launch_bounds__(256) void reduce_rep(
    const float4* __restrict__ rep,   // [NREP][n4]
    float4* __restrict__ out,         // [n4]
    int n4)
{
    int k = blockIdx.x * blockDim.x + threadIdx.x;
    if (k >= n4) return;
    float4 s = rep[k];
    #pragma unroll
    for (int r = 1; r < NREP; ++r) {
        float4 t = rep[(size_t)r * n4 + k];
        s.x += t.x; s.y += t.y; s.z += t.z; s.w += t.w;
    }
    out[k] = s;
}

extern "C" void kernel_launch(void* const* d_in, const int* in_sizes, int n_in,
                              void* d_out, int out_size, void* d_ws, size_t ws_size,
                              hipStream_t stream)
{
    // inputs: charges, cell, positions, neighbor_indices, neighbor_distances
    const float4* charges = (const float4*)d_in[0];
    const int2*   nbr     = (const int2*)d_in[3];
    const float*  dist    = (const float*)d_in[4];
    float*        out     = (float*)d_out;

    int n_edges   = in_sizes[4];           // 12,800,000
    int atoms_nch = out_size;              // N_ATOMS * NCH = 800,000
    size_t rep_bytes = (size_t)NREP * atoms_nch * sizeof(float);

    int block = 256;
    int grid  = (n_edges + block - 1) / block;

    if (ws_size >= rep_bytes) {
        float* rep = (float*)d_ws;
        hipMemsetAsync(rep, 0, rep_bytes, stream);   // ws is poisoned 0xAA
        edge_scatter_rep<<<grid, block, 0, stream>>>(charges, nbr, dist, rep,
                                                     n_edges, atoms_nch);
        int n4 = atoms_nch / 4;
        reduce_rep<<<(n4 + block - 1) / block, block, 0, stream>>>(
            (const float4*)rep, (float4*)out, n4);
    } else {
        hipMemsetAsync(d_out, 0, (size_t)out_size * sizeof(float), stream);
        edge_scatter_agent<<<grid, block, 0, stream>>>(charges, nbr, dist, out,
                                                       n_edges);
    }
}

// Round 3
// 1043.182 us; speedup vs baseline: 4.9209x; 4.9184x over previous
//
#include <hip/hip_runtime.h>

// Round-1/2 learning: global f32 atomicAdd on gfx950 is memory-side at ANY
// scope: 102.4M atomics x 32B = 3.28 GB write-through @ ~674 GB/s = 5 ms.
// Round-3: eliminate global atomics entirely.
//   K1 per-block LDS histograms over 98 atom-buckets (2048 atoms each)
//   K2 row scan + K3 bucket bases + K4 add bases  -> exact scatter offsets
//   K5 counting-sort scatter of 25.6M 8B tuples (dest_local | src<<11, w)
//   K6 per-(bucket,slice) LDS accumulation with ds_add_f32 (CU-local, fast)
//   K7 reduce 4 slice partials -> out
// No global atomics anywhere; no memsets needed (every ws byte we read is
// written unconditionally first).

#define BLOCK   256
#define NBLK    512        // edge chunks for hist/scatter
#define AB_LOG  11
#define A_B     2048       // atoms per bucket (32 KB LDS accumulator)
#define MAXNB   128
#define NSLICE  4

static __device__ __forceinline__ unsigned long long nt_u64(const void* p) {
    return __builtin_nontemporal_load((const unsigned long long*)p);
}
static __device__ __forceinline__ float nt_f32(const float* p) {
    return __builtin_nontemporal_load(p);
}

// ---- K1: per-block histogram over buckets -------------------------------
__global__ __launch_bounds__(BLOCK) void k_hist(
    const int2* __restrict__ nbr, int* __restrict__ blk_hist,
    int n_edges, int nb)
{
    __shared__ int h[MAXNB];
    for (int i = threadIdx.x; i < nb; i += blockDim.x) h[i] = 0;
    __syncthreads();
    int per = (n_edges + gridDim.x - 1) / gridDim.x;
    int lo = blockIdx.x * per;
    int hi = min(lo + per, n_edges);
    for (int e = lo + threadIdx.x; e < hi; e += blockDim.x) {
        int2 ij = nbr[e];
        atomicAdd(&h[ij.x >> AB_LOG], 1);
        atomicAdd(&h[ij.y >> AB_LOG], 1);
    }
    __syncthreads();
    for (int i = threadIdx.x; i < nb; i += blockDim.x)
        blk_hist[i * NBLK + blockIdx.x] = h[i];
}

// ---- K2: exclusive scan of each bucket's row (512 entries) --------------
__global__ __launch_bounds__(NBLK) void k_rowscan(
    const int* __restrict__ blk_hist, int* __restrict__ offs,
    int* __restrict__ totals)
{
    __shared__ int a[NBLK];
    int b = blockIdx.x, t = threadIdx.x;
    int v = blk_hist[b * NBLK + t];
    a[t] = v;
    __syncthreads();
    for (int off = 1; off < NBLK; off <<= 1) {
        int x = (t >= off) ? a[t - off] : 0;
        __syncthreads();
        a[t] += x;
        __syncthreads();
    }
    offs[b * NBLK + t] = a[t] - v;       // exclusive, base added later
    if (t == NBLK - 1) totals[b] = a[t];
}

// ---- K3: bucket bases (tiny serial scan) --------------------------------
__global__ void k_bases(const int* __restrict__ totals, int* __restrict__ bases, int nb)
{
    if (threadIdx.x == 0) {
        int s = 0;
        for (int b = 0; b < nb; ++b) { bases[b] = s; s += totals[b]; }
    }
}

// ---- K4: offs[i] += bases[i / NBLK] -------------------------------------
__global__ void k_addbase(int* __restrict__ offs, const int* __restrict__ bases, int n)
{
    int i = blockIdx.x * blockDim.x + threadIdx.x;
    if (i < n) offs[i] += bases[i >> 9];   // NBLK == 512
}

// ---- K5: counting-sort scatter of tuples --------------------------------
__global__ __launch_bounds__(BLOCK) void k_scatter(
    const int2* __restrict__ nbr, const float* __restrict__ dist,
    const int* __restrict__ offs, uint2* __restrict__ tuples,
    int n_edges, int nb)
{
    __shared__ int cur[MAXNB];
    for (int i = threadIdx.x; i < nb; i += blockDim.x)
        cur[i] = offs[i * NBLK + blockIdx.x];
    __syncthreads();
    int per = (n_edges + gridDim.x - 1) / gridDim.x;
    int lo = blockIdx.x * per;
    int hi = min(lo + per, n_edges);
    for (int e = lo + threadIdx.x; e < hi; e += blockDim.x) {
        unsigned long long v = nt_u64(&nbr[e]);
        int ix = (int)(v & 0xffffffffu);
        int iy = (int)(v >> 32);
        float w = 0.5f / nt_f32(&dist[e]);
        unsigned wb = __float_as_uint(w);
        int pi = atomicAdd(&cur[ix >> AB_LOG], 1);
        tuples[pi] = make_uint2((unsigned)(ix & (A_B - 1)) | ((unsigned)iy << AB_LOG), wb);
        int pj = atomicAdd(&cur[iy >> AB_LOG], 1);
        tuples[pj] = make_uint2((unsigned)(iy & (A_B - 1)) | ((unsigned)ix << AB_LOG), wb);
    }
}

// ---- K6: per-(bucket,slice) LDS accumulation ----------------------------
__global__ __launch_bounds__(BLOCK) void k_accum(
    const uint2* __restrict__ tuples, const float4* __restrict__ charges,
    const int* __restrict__ bases, const int* __restrict__ totals,
    float* __restrict__ partials)
{
    __shared__ float acc[A_B * 4];     // 32 KB
    int b = blockIdx.x >> 2;           // NSLICE == 4
    int s = blockIdx.x & 3;
    for (int i = threadIdx.x; i < A_B * 4; i += blockDim.x) acc[i] = 0.f;
    __syncthreads();
    int start = bases[b], cnt = totals[b];
    int lo = start + cnt * s / NSLICE;
    int hi = start + cnt * (s + 1) / NSLICE;
    for (int p = lo + threadIdx.x; p < hi; p += blockDim.x) {
        unsigned long long v = nt_u64(&tuples[p]);
        unsigned packed = (unsigned)(v & 0xffffffffu);
        float w = __uint_as_float((unsigned)(v >> 32));
        int dest = packed & (A_B - 1);
        int src  = packed >> AB_LOG;
        float4 c = charges[src];
        atomicAdd(&acc[dest * 4 + 0], c.x * w);
        atomicAdd(&acc[dest * 4 + 1], c.y * w);
        atomicAdd(&acc[dest * 4 + 2], c.z * w);
        atomicAdd(&acc[dest * 4 + 3], c.w * w);
    }
    __syncthreads();
    float* outp = partials + (size_t)blockIdx.x * (A_B * 4);
    for (int i = threadIdx.x; i < A_B * 4; i += blockDim.x) outp[i] = acc[i];
}

// ---- K7: reduce NSLICE partial images -> out ----------------------------
__global__ void k_final(const float4* __restrict__ partials,
                        float4* __restrict__ out, int n_atoms)
{
    int a = blockIdx.x * blockDim.x + threadIdx.x;
    if (a >= n_atoms) return;
    int b = a >> AB_LOG;
    int local = a & (A_B - 1);
    const float4* p = partials + (size_t)(b * NSLICE) * A_B + local;
    float4 s0 = p[0], s1 = p[A_B], s2 = p[2 * A_B], s3 = p[3 * A_B];
    float4 r;
    r.x = s0.x + s1.x + s2.x + s3.x;
    r.y = s0.y + s1.y + s2.y + s3.y;
    r.z = s0.z + s1.z + s2.z + s3.z;
    r.w = s0.w + s1.w + s2.w + s3.w;
    out[a] = r;
}

// ---- fallback (ws too small): agent-scope atomics, correct but 5 ms -----
__global__ __launch_bounds__(BLOCK) void edge_scatter_agent(
    const float4* __restrict__ charges, const int2* __restrict__ nbr,
    const float* __restrict__ dist, float* __restrict__ out, int n_edges)
{
    int e = blockIdx.x * blockDim.x + threadIdx.x;
    if (e >= n_edges) return;
    int2 ij = nbr[e];
    float w = 0.5f / dist[e];
    float4 cj = charges[ij.y];
    float4 ci = charges[ij.x];
    float* oi = out + (size_t)ij.x * 4;
    float* oj = out + (size_t)ij.y * 4;
    atomicAdd(oi + 0, cj.x * w); atomicAdd(oi + 1, cj.y * w);
    atomicAdd(oi + 2, cj.z * w); atomicAdd(oi + 3, cj.w * w);
    atomicAdd(oj + 0, ci.x * w); atomicAdd(oj + 1, ci.y * w);
    atomicAdd(oj + 2, ci.z * w); atomicAdd(oj + 3, ci.w * w);
}

extern "C" void kernel_launch(void* const* d_in, const int* in_sizes, int n_in,
                              void* d_out, int out_size, void* d_ws, size_t ws_size,
                              hipStream_t stream)
{
    // inputs: charges, cell, positions, neighbor_indices, neighbor_distances
    const float4* charges = (const float4*)d_in[0];
    const int2*   nbr     = (const int2*)d_in[3];
    const float*  dist    = (const float*)d_in[4];

    int n_edges = in_sizes[4];
    int n_atoms = out_size / 4;
    int nb = (n_atoms + A_B - 1) >> AB_LOG;     // 98 for 200000 atoms

    size_t n_pairs = (size_t)2 * n_edges;
    char*  w   = (char*)d_ws;
    size_t off = 0;
    auto alloc = [&](size_t bytes) -> void* {
        void* p = w + off;
        off += (bytes + 255) & ~(size_t)255;
        return p;
    };
    uint2* tuples   = (uint2*)alloc(n_pairs * sizeof(uint2));
    int*   blk_hist = (int*)  alloc((size_t)nb * NBLK * sizeof(int));
    int*   offs     = (int*)  alloc((size_t)nb * NBLK * sizeof(int));
    int*   totals   = (int*)  alloc((size_t)nb * sizeof(int));
    int*   bases    = (int*)  alloc((size_t)nb * sizeof(int));
    float* partials = (float*)alloc((size_t)nb * NSLICE * A_B * 4 * sizeof(float));

    if (off <= ws_size && nb <= MAXNB) {
        k_hist   <<<NBLK, BLOCK, 0, stream>>>(nbr, blk_hist, n_edges, nb);
        k_rowscan<<<nb,   NBLK,  0, stream>>>(blk_hist, offs, totals);
        k_bases  <<<1,    64,    0, stream>>>(totals, bases, nb);
        k_addbase<<<(nb * NBLK + 255) / 256, 256, 0, stream>>>(offs, bases, nb * NBLK);
        k_scatter<<<NBLK, BLOCK, 0, stream>>>(nbr, dist, offs, tuples, n_edges, nb);
        k_accum  <<<nb * NSLICE, BLOCK, 0, stream>>>(tuples, charges, bases, totals, partials);
        k_final  <<<(n_atoms + 255) / 256, 256, 0, stream>>>(
            (const float4*)partials, (float4*)d_out, n_atoms);
    } else {
        hipMemsetAsync(d_out, 0, (size_t)out_size * sizeof(float), stream);
        edge_scatter_agent<<<(n_edges + BLOCK - 1) / BLOCK, BLOCK, 0, stream>>>(
            charges, nbr, dist, (float*)d_out, n_edges);
    }
}

// Round 4
// 1029.788 us; speedup vs baseline: 4.9849x; 1.0130x over previous
//
#include <hip/hip_runtime.h>

// Counting-sort + LDS accumulation (no global atomics anywhere).
// R3 -> R4: k_accum was latency-bound at 13.7% occupancy (392 blocks, no MLP).
//   - A_B 2048->1024 (16 KB LDS, 10 blocks/CU), NSLICE 4->8 (adaptive)
//   - unroll x4 batched loads in k_accum (4 tuple loads -> 4 gathers -> 16 ds_add)
//   - NBLK 512->1024 for hist/scatter; k_bases serial -> parallel LDS scan

#define BLOCK   256
#define NBLK    1024       // edge chunks for hist/scatter (== rowscan width)
#define NBLK_LG 10
#define AB_LOG  10
#define A_B     1024       // atoms per bucket (16 KB LDS accumulator)
#define MAXNB   256

static __device__ __forceinline__ unsigned long long nt_u64(const void* p) {
    return __builtin_nontemporal_load((const unsigned long long*)p);
}
static __device__ __forceinline__ float nt_f32(const float* p) {
    return __builtin_nontemporal_load(p);
}

// ---- K1: per-block histogram over buckets -------------------------------
__global__ __launch_bounds__(BLOCK) void k_hist(
    const int2* __restrict__ nbr, int* __restrict__ blk_hist,
    int n_edges, int nb)
{
    __shared__ int h[MAXNB];
    for (int i = threadIdx.x; i < nb; i += blockDim.x) h[i] = 0;
    __syncthreads();
    int per = (n_edges + gridDim.x - 1) / gridDim.x;
    int lo = blockIdx.x * per;
    int hi = min(lo + per, n_edges);
    #pragma unroll 4
    for (int e = lo + threadIdx.x; e < hi; e += blockDim.x) {
        unsigned long long v = nt_u64(&nbr[e]);
        int ix = (int)(v & 0xffffffffu);
        int iy = (int)(v >> 32);
        atomicAdd(&h[ix >> AB_LOG], 1);
        atomicAdd(&h[iy >> AB_LOG], 1);
    }
    __syncthreads();
    for (int i = threadIdx.x; i < nb; i += blockDim.x)
        blk_hist[i * NBLK + blockIdx.x] = h[i];
}

// ---- K2: exclusive scan of each bucket's row (NBLK entries) -------------
__global__ __launch_bounds__(NBLK) void k_rowscan(
    const int* __restrict__ blk_hist, int* __restrict__ offs,
    int* __restrict__ totals)
{
    __shared__ int a[NBLK];
    int b = blockIdx.x, t = threadIdx.x;
    int v = blk_hist[b * NBLK + t];
    a[t] = v;
    __syncthreads();
    for (int off = 1; off < NBLK; off <<= 1) {
        int x = (t >= off) ? a[t - off] : 0;
        __syncthreads();
        a[t] += x;
        __syncthreads();
    }
    offs[b * NBLK + t] = a[t] - v;       // exclusive within bucket
    if (t == NBLK - 1) totals[b] = a[t];
}

// ---- K3: bucket bases (parallel LDS scan, one block) --------------------
__global__ __launch_bounds__(MAXNB) void k_bases(
    const int* __restrict__ totals, int* __restrict__ bases, int nb)
{
    __shared__ int a[MAXNB];
    int t = threadIdx.x;
    int v = (t < nb) ? totals[t] : 0;
    a[t] = v;
    __syncthreads();
    for (int off = 1; off < MAXNB; off <<= 1) {
        int x = (t >= off) ? a[t - off] : 0;
        __syncthreads();
        a[t] += x;
        __syncthreads();
    }
    if (t < nb) bases[t] = a[t] - v;
}

// ---- K4: offs[i] += bases[i / NBLK] -------------------------------------
__global__ void k_addbase(int* __restrict__ offs, const int* __restrict__ bases, int n)
{
    int i = blockIdx.x * blockDim.x + threadIdx.x;
    if (i < n) offs[i] += bases[i >> NBLK_LG];
}

// ---- K5: counting-sort scatter of tuples --------------------------------
__global__ __launch_bounds__(BLOCK) void k_scatter(
    const int2* __restrict__ nbr, const float* __restrict__ dist,
    const int* __restrict__ offs, uint2* __restrict__ tuples,
    int n_edges, int nb)
{
    __shared__ int cur[MAXNB];
    for (int i = threadIdx.x; i < nb; i += blockDim.x)
        cur[i] = offs[i * NBLK + blockIdx.x];
    __syncthreads();
    int per = (n_edges + gridDim.x - 1) / gridDim.x;
    int lo = blockIdx.x * per;
    int hi = min(lo + per, n_edges);
    #pragma unroll 2
    for (int e = lo + threadIdx.x; e < hi; e += blockDim.x) {
        unsigned long long v = nt_u64(&nbr[e]);
        int ix = (int)(v & 0xffffffffu);
        int iy = (int)(v >> 32);
        float w = 0.5f / nt_f32(&dist[e]);
        unsigned wb = __float_as_uint(w);
        int pi = atomicAdd(&cur[ix >> AB_LOG], 1);
        tuples[pi] = make_uint2((unsigned)(ix & (A_B - 1)) | ((unsigned)iy << AB_LOG), wb);
        int pj = atomicAdd(&cur[iy >> AB_LOG], 1);
        tuples[pj] = make_uint2((unsigned)(iy & (A_B - 1)) | ((unsigned)ix << AB_LOG), wb);
    }
}

// ---- K6: per-(bucket,slice) LDS accumulation, unroll x4 -----------------
__global__ __launch_bounds__(BLOCK) void k_accum(
    const uint2* __restrict__ tuples, const float4* __restrict__ charges,
    const int* __restrict__ bases, const int* __restrict__ totals,
    float* __restrict__ partials, int nslice)
{
    __shared__ float acc[A_B * 4];     // 16 KB
    int b = blockIdx.x / nslice;
    int s = blockIdx.x % nslice;
    for (int i = threadIdx.x; i < A_B * 4; i += blockDim.x) acc[i] = 0.f;
    __syncthreads();
    int start = bases[b], cnt = totals[b];
    int lo = start + (int)((long long)cnt * s / nslice);
    int hi = start + (int)((long long)cnt * (s + 1) / nslice);

    int p = lo + threadIdx.x;
    for (; p + 3 * BLOCK < hi; p += 4 * BLOCK) {
        uint2 t0 = tuples[p];
        uint2 t1 = tuples[p + BLOCK];
        uint2 t2 = tuples[p + 2 * BLOCK];
        uint2 t3 = tuples[p + 3 * BLOCK];
        float4 c0 = charges[t0.x >> AB_LOG];
        float4 c1 = charges[t1.x >> AB_LOG];
        float4 c2 = charges[t2.x >> AB_LOG];
        float4 c3 = charges[t3.x >> AB_LOG];
        float w0 = __uint_as_float(t0.y), w1 = __uint_as_float(t1.y);
        float w2 = __uint_as_float(t2.y), w3 = __uint_as_float(t3.y);
        int d0 = (t0.x & (A_B - 1)) * 4, d1 = (t1.x & (A_B - 1)) * 4;
        int d2 = (t2.x & (A_B - 1)) * 4, d3 = (t3.x & (A_B - 1)) * 4;
        atomicAdd(&acc[d0 + 0], c0.x * w0); atomicAdd(&acc[d0 + 1], c0.y * w0);
        atomicAdd(&acc[d0 + 2], c0.z * w0); atomicAdd(&acc[d0 + 3], c0.w * w0);
        atomicAdd(&acc[d1 + 0], c1.x * w1); atomicAdd(&acc[d1 + 1], c1.y * w1);
        atomicAdd(&acc[d1 + 2], c1.z * w1); atomicAdd(&acc[d1 + 3], c1.w * w1);
        atomicAdd(&acc[d2 + 0], c2.x * w2); atomicAdd(&acc[d2 + 1], c2.y * w2);
        atomicAdd(&acc[d2 + 2], c2.z * w2); atomicAdd(&acc[d2 + 3], c2.w * w2);
        atomicAdd(&acc[d3 + 0], c3.x * w3); atomicAdd(&acc[d3 + 1], c3.y * w3);
        atomicAdd(&acc[d3 + 2], c3.z * w3); atomicAdd(&acc[d3 + 3], c3.w * w3);
    }
    for (; p < hi; p += BLOCK) {
        uint2 t = tuples[p];
        float4 c = charges[t.x >> AB_LOG];
        float w = __uint_as_float(t.y);
        int d = (t.x & (A_B - 1)) * 4;
        atomicAdd(&acc[d + 0], c.x * w); atomicAdd(&acc[d + 1], c.y * w);
        atomicAdd(&acc[d + 2], c.z * w); atomicAdd(&acc[d + 3], c.w * w);
    }
    __syncthreads();
    float* outp = partials + (size_t)blockIdx.x * (A_B * 4);
    for (int i = threadIdx.x; i < A_B * 4; i += blockDim.x) outp[i] = acc[i];
}

// ---- K7: reduce nslice partial images -> out ----------------------------
__global__ void k_final(const float4* __restrict__ partials,
                        float4* __restrict__ out, int n_atoms, int nslice)
{
    int a = blockIdx.x * blockDim.x + threadIdx.x;
    if (a >= n_atoms) return;
    int b = a >> AB_LOG;
    int local = a & (A_B - 1);
    const float4* p = partials + (size_t)(b * nslice) * A_B + local;
    float4 r = make_float4(0.f, 0.f, 0.f, 0.f);
    for (int s = 0; s < nslice; ++s) {
        float4 t = p[(size_t)s * A_B];
        r.x += t.x; r.y += t.y; r.z += t.z; r.w += t.w;
    }
    out[a] = r;
}

// ---- fallback (ws too small): agent-scope atomics, correct but 5 ms -----
__global__ __launch_bounds__(BLOCK) void edge_scatter_agent(
    const float4* __restrict__ charges, const int2* __restrict__ nbr,
    const float* __restrict__ dist, float* __restrict__ out, int n_edges)
{
    int e = blockIdx.x * blockDim.x + threadIdx.x;
    if (e >= n_edges) return;
    int2 ij = nbr[e];
    float w = 0.5f / dist[e];
    float4 cj = charges[ij.y];
    float4 ci = charges[ij.x];
    float* oi = out + (size_t)ij.x * 4;
    float* oj = out + (size_t)ij.y * 4;
    atomicAdd(oi + 0, cj.x * w); atomicAdd(oi + 1, cj.y * w);
    atomicAdd(oi + 2, cj.z * w); atomicAdd(oi + 3, cj.w * w);
    atomicAdd(oj + 0, ci.x * w); atomicAdd(oj + 1, ci.y * w);
    atomicAdd(oj + 2, ci.z * w); atomicAdd(oj + 3, ci.w * w);
}

extern "C" void kernel_launch(void* const* d_in, const int* in_sizes, int n_in,
                              void* d_out, int out_size, void* d_ws, size_t ws_size,
                              hipStream_t stream)
{
    // inputs: charges, cell, positions, neighbor_indices, neighbor_distances
    const float4* charges = (const float4*)d_in[0];
    const int2*   nbr     = (const int2*)d_in[3];
    const float*  dist    = (const float*)d_in[4];

    int n_edges = in_sizes[4];
    int n_atoms = out_size / 4;
    int nb = (n_atoms + A_B - 1) >> AB_LOG;     // 196 for 200000 atoms

    size_t n_pairs = (size_t)2 * n_edges;
    char*  w   = (char*)d_ws;
    size_t off = 0;
    auto alloc = [&](size_t bytes) -> void* {
        void* p = w + off;
        off += (bytes + 255) & ~(size_t)255;
        return p;
    };
    uint2* tuples   = (uint2*)alloc(n_pairs * sizeof(uint2));
    int*   blk_hist = (int*)  alloc((size_t)nb * NBLK * sizeof(int));
    int*   offs     = (int*)  alloc((size_t)nb * NBLK * sizeof(int));
    int*   totals   = (int*)  alloc((size_t)nb * sizeof(int));
    int*   bases    = (int*)  alloc((size_t)nb * sizeof(int));

    // adaptive slice count: partials = nb*nslice*A_B*4*4 bytes
    size_t slice_bytes = (size_t)nb * A_B * 4 * sizeof(float);
    int nslice = 16;
    while (nslice > 1 && off + (size_t)nslice * slice_bytes > ws_size) nslice >>= 1;
    float* partials = (float*)alloc((size_t)nslice * slice_bytes);

    if (off <= ws_size && nb <= MAXNB) {
        k_hist   <<<NBLK, BLOCK, 0, stream>>>(nbr, blk_hist, n_edges, nb);
        k_rowscan<<<nb,   NBLK,  0, stream>>>(blk_hist, offs, totals);
        k_bases  <<<1,    MAXNB, 0, stream>>>(totals, bases, nb);
        k_addbase<<<(nb * NBLK + 255) / 256, 256, 0, stream>>>(offs, bases, nb * NBLK);
        k_scatter<<<NBLK, BLOCK, 0, stream>>>(nbr, dist, offs, tuples, n_edges, nb);
        k_accum  <<<nb * nslice, BLOCK, 0, stream>>>(tuples, charges, bases, totals,
                                                     partials, nslice);
        k_final  <<<(n_atoms + 255) / 256, 256, 0, stream>>>(
            (const float4*)partials, (float4*)d_out, n_atoms, nslice);
    } else {
        hipMemsetAsync(d_out, 0, (size_t)out_size * sizeof(float), stream);
        edge_scatter_agent<<<(n_edges + BLOCK - 1) / BLOCK, BLOCK, 0, stream>>>(
            charges, nbr, dist, (float*)d_out, n_edges);
    }
}